// Round 15
// baseline (151.888 us; speedup 1.0000x reference)
//
#include <hip/hip_runtime.h>
#include <hip/hip_bf16.h>

// Problem constants
#define B_  8
#define TQ_ 128
#define TK_ 512
#define D_  256
#define H_  256

#define KSCALE 2.8853900817779268f   // 2*log2(e): exp(2x) = exp2(KSCALE*x)

__device__ __forceinline__ float fast_exp2(float x) {
    return __builtin_amdgcn_exp2f(x);   // v_exp_f32: 2^x
}
__device__ __forceinline__ float fast_rcp(float y) {
    return __builtin_amdgcn_rcpf(y);
}

__device__ __forceinline__ float wave_red_min(float v) {
#pragma unroll
    for (int o = 32; o > 0; o >>= 1) v = fminf(v, __shfl_xor(v, o));
    return v;
}
__device__ __forceinline__ float wave_red_sum(float v) {
#pragma unroll
    for (int o = 32; o > 0; o >>= 1) v += __shfl_xor(v, o);
    return v;
}

// ---------------------------------------------------------------------------
// Kernel 1: projections, outputs pre-scaled by KSCALE. 16-row tiles.
//   blocks [0,64):   qp[b][q][h]  = KSCALE * queries·Wq  (row-major)
//   blocks [64,320): kpT[b][h][k] = KSCALE * keys·Wk     (transposed; tile
//                    skipped when r0 >= valid_lens[b])
// 512 threads: hq = t&63 (h0=hq*4), rg = t>>6 (rows 2rg, 2rg+1).
// W loads are float4 over h (contiguous 1KB per wave per d).
// ---------------------------------------------------------------------------
__global__ __launch_bounds__(512) void proj_kernel(
    const float* __restrict__ queries, const float* __restrict__ keys,
    const float* __restrict__ Wq, const float* __restrict__ Wk,
    const int* __restrict__ valid_lens,
    float* __restrict__ qp, float* __restrict__ kpT)
{
    __shared__ __align__(16) float4 xs4[16 * 64];   // 16 rows x 256 d
    __shared__ __align__(16) float tile[16 * 260];  // transpose staging (k path)

    const int t = threadIdx.x;
    const bool isQ = (blockIdx.x < 64);
    const float* X; const float* W; int b, r0;
    if (isQ) {
        b = blockIdx.x >> 3; r0 = (blockIdx.x & 7) * 16;
        X = queries + ((size_t)b * TQ_ + r0) * D_;  W = Wq;
    } else {
        int id = blockIdx.x - 64;
        b = id >> 5; r0 = (id & 31) * 16;
        if (r0 >= valid_lens[b]) return;   // masked keys never read downstream
        X = keys + ((size_t)b * TK_ + r0) * D_;     W = Wk;
    }

    // stage 16 x 256 input tile as float4 (coalesced)
    const float4* X4 = reinterpret_cast<const float4*>(X);
    xs4[t]       = X4[t];
    xs4[t + 512] = X4[t + 512];
    __syncthreads();

    const int hq = t & 63;          // h0 = hq*4
    const int rg = t >> 6;          // 0..7
    const int rA = rg * 2, rB = rA + 1;
    const float4* W4 = reinterpret_cast<const float4*>(W) + hq;

    float4 a0 = make_float4(0.f, 0.f, 0.f, 0.f);
    float4 a1 = make_float4(0.f, 0.f, 0.f, 0.f);

#pragma unroll 4
    for (int d4 = 0; d4 < 64; ++d4) {
        const float4 xa = xs4[rA * 64 + d4];
        const float4 xb = xs4[rB * 64 + d4];
        const float4 w0 = W4[(size_t)(d4 * 4 + 0) * 64];
        const float4 w1 = W4[(size_t)(d4 * 4 + 1) * 64];
        const float4 w2 = W4[(size_t)(d4 * 4 + 2) * 64];
        const float4 w3 = W4[(size_t)(d4 * 4 + 3) * 64];
        a0.x = fmaf(w0.x, xa.x, a0.x); a0.y = fmaf(w0.y, xa.x, a0.y);
        a0.z = fmaf(w0.z, xa.x, a0.z); a0.w = fmaf(w0.w, xa.x, a0.w);
        a1.x = fmaf(w0.x, xb.x, a1.x); a1.y = fmaf(w0.y, xb.x, a1.y);
        a1.z = fmaf(w0.z, xb.x, a1.z); a1.w = fmaf(w0.w, xb.x, a1.w);
        a0.x = fmaf(w1.x, xa.y, a0.x); a0.y = fmaf(w1.y, xa.y, a0.y);
        a0.z = fmaf(w1.z, xa.y, a0.z); a0.w = fmaf(w1.w, xa.y, a0.w);
        a1.x = fmaf(w1.x, xb.y, a1.x); a1.y = fmaf(w1.y, xb.y, a1.y);
        a1.z = fmaf(w1.z, xb.y, a1.z); a1.w = fmaf(w1.w, xb.y, a1.w);
        a0.x = fmaf(w2.x, xa.z, a0.x); a0.y = fmaf(w2.y, xa.z, a0.y);
        a0.z = fmaf(w2.z, xa.z, a0.z); a0.w = fmaf(w2.w, xa.z, a0.w);
        a1.x = fmaf(w2.x, xb.z, a1.x); a1.y = fmaf(w2.y, xb.z, a1.y);
        a1.z = fmaf(w2.z, xb.z, a1.z); a1.w = fmaf(w2.w, xb.z, a1.w);
        a0.x = fmaf(w3.x, xa.w, a0.x); a0.y = fmaf(w3.y, xa.w, a0.y);
        a0.z = fmaf(w3.z, xa.w, a0.z); a0.w = fmaf(w3.w, xa.w, a0.w);
        a1.x = fmaf(w3.x, xb.w, a1.x); a1.y = fmaf(w3.y, xb.w, a1.y);
        a1.z = fmaf(w3.z, xb.w, a1.z); a1.w = fmaf(w3.w, xb.w, a1.w);
    }
    a0.x *= KSCALE; a0.y *= KSCALE; a0.z *= KSCALE; a0.w *= KSCALE;
    a1.x *= KSCALE; a1.y *= KSCALE; a1.z *= KSCALE; a1.w *= KSCALE;

    if (isQ) {
        float* dst = qp + ((size_t)b * TQ_ + r0) * H_ + hq * 4;
        *reinterpret_cast<float4*>(dst + (size_t)rA * H_) = a0;
        *reinterpret_cast<float4*>(dst + (size_t)rB * H_) = a1;
    } else {
        // transpose through LDS: tile[r][h], then write kpT[h][k] in 32B chunks
        *reinterpret_cast<float4*>(&tile[rA * 260 + hq * 4]) = a0;
        *reinterpret_cast<float4*>(&tile[rB * 260 + hq * 4]) = a1;
        __syncthreads();
        const int h = t >> 1, half = t & 1;
        float v[8];
#pragma unroll
        for (int i = 0; i < 8; ++i) v[i] = tile[(half * 8 + i) * 260 + h];
        float* dst = kpT + (size_t)b * (H_ * TK_) + (size_t)h * TK_ + r0 + half * 8;
        *reinterpret_cast<float4*>(dst)     = make_float4(v[0], v[1], v[2], v[3]);
        *reinterpret_cast<float4*>(dst + 4) = make_float4(v[4], v[5], v[6], v[7]);
    }
}

// ---------------------------------------------------------------------------
// Kernel 2: fused scores + masked softmax + PV. ONE q-row per block,
// 256 threads, 1024 blocks (b fastest) -> ~4KB LDS, high residency; short-len
// blocks retire early and the scheduler backfills (wall -> mean-len work).
// Score: thread t owns k = {2t, 2t+1} (float2 kpT load, 512B/wave contiguous);
// wave w covers k in [128w, 128w+128) and skips when len <= 128w.
// softmax(score) == softmax over k of exp2(KSCALE*(accmin - acc)).
// PV: thread t = d; scalar k loop with dead 64-k chunks skipped.
// ---------------------------------------------------------------------------
__global__ __launch_bounds__(256) void attn_kernel(
    const float* __restrict__ qp, const float* __restrict__ kpT,
    const float* __restrict__ values, const int* __restrict__ valid_lens,
    const float* __restrict__ wv, float* __restrict__ out)
{
    __shared__ __align__(16) float qw[H_], wvs[H_];
    __shared__ __align__(16) float2 pe2[TK_ / 2];   // pe[2t], pe[2t+1]
    __shared__ float redm[4], reds[4];

    const int t = threadIdx.x;
    const int b = blockIdx.x;                 // fastest-varying: batch mix
    const int q = blockIdx.y;
    const int len = valid_lens[b];

    // stage q-row + wv
    const float* qpb = qp + ((size_t)b * TQ_ + q) * H_;
    qw[t]  = qpb[t];
    wvs[t] = wv[t];
    __syncthreads();

    // ---- score: k0 = 2t, k1 = 2t+1; wave-uniform 128-k skip ----
    const int wid = t >> 6, lane = t & 63;
    const int k0 = 2 * t;
    float a0 = 0.f, a1 = 0.f;
    if (wid * 128 < len) {
        const float* kb = kpT + (size_t)b * (H_ * TK_) + k0;
#pragma unroll 4
        for (int h = 0; h < H_; ++h) {
            const float2 kk = *reinterpret_cast<const float2*>(kb + (size_t)h * TK_);
            const float qv = qw[h];
            const float w  = wvs[h];
            a0 = fmaf(w, fast_rcp(1.0f + fast_exp2(qv + kk.x)), a0);
            a1 = fmaf(w, fast_rcp(1.0f + fast_exp2(qv + kk.y)), a1);
        }
    }

    // ---- masked softmax over k (min of acc == max of score) ----
    const bool v0 = (k0 < len), v1 = (k0 + 1 < len);
    const float BIG = 3.0e38f;

    float m = fminf(v0 ? a0 : BIG, v1 ? a1 : BIG);
    m = wave_red_min(m);
    if (lane == 0) redm[wid] = m;
    __syncthreads();
    const float mr = fminf(fminf(redm[0], redm[1]), fminf(redm[2], redm[3]));

    const float e0 = v0 ? fast_exp2((mr - a0) * KSCALE) : 0.f;
    const float e1 = v1 ? fast_exp2((mr - a1) * KSCALE) : 0.f;
    pe2[t] = make_float2(e0, e1);
    float S = wave_red_sum(e0 + e1);
    if (lane == 0) reds[wid] = S;
    __syncthreads();
    const float rs = 1.0f / (((reds[0] + reds[1]) + (reds[2] + reds[3])));

    // ---- PV: thread t = d; dead 64-k chunks skipped ----
    const float* pes = reinterpret_cast<const float*>(pe2);
    const float* vb  = values + (size_t)b * (TK_ * D_) + t;
    float c = 0.f;
#pragma unroll
    for (int ch = 0; ch < 8; ++ch) {
        if (ch * 64 < len) {
#pragma unroll 8
            for (int i = 0; i < 64; ++i) {
                const int kk = ch * 64 + i;
                c = fmaf(pes[kk], vb[(size_t)kk * D_], c);
            }
        }
    }
    out[((size_t)b * TQ_ + q) * D_ + t] = c * rs;
}

extern "C" void kernel_launch(void* const* d_in, const int* in_sizes, int n_in,
                              void* d_out, int out_size, void* d_ws, size_t ws_size,
                              hipStream_t stream) {
    const float* queries    = (const float*)d_in[0];
    const float* keys       = (const float*)d_in[1];
    const float* values     = (const float*)d_in[2];
    const int*   valid_lens = (const int*)  d_in[3];
    const float* Wq         = (const float*)d_in[4];
    const float* Wk         = (const float*)d_in[5];
    const float* wv         = (const float*)d_in[6];
    float* out = (float*)d_out;

    float* qp  = (float*)d_ws;                       // B*Tq*H  = 262144 f32
    float* kpT = qp + (size_t)B_ * TQ_ * H_;         // B*H*Tk  = 1048576 f32

    proj_kernel<<<320, 512, 0, stream>>>(queries, keys, Wq, Wk, valid_lens, qp, kpT);
    attn_kernel<<<dim3(B_, TQ_), 256, 0, stream>>>(qp, kpT, values, valid_lens, wv, out);
}